// Round 3
// baseline (642.564 us; speedup 1.0000x reference)
//
#include <hip/hip_runtime.h>

// ConvMultiStepAttention, B=16, C=T=S=1024, fp32 in/out.
// R5: counted-vmcnt double-buffer (T4) in all three GEMMs:
//   per K-step: STAGE(next tile -> buf^1); s_waitcnt vmcnt(8) [waits only the
//   PREVIOUS tile's loads, current prefetch stays in flight]; raw s_barrier;
//   ds_read+MFMA from buf[cur]; raw s_barrier. Never vmcnt(0) in main loop
//   (m218: counted-vs-drain = +38..73%). Numerics identical to R4 (fp16
//   hi/lo 3-product split in gemm1/2, plain fp16 gemm3).
// Buffer plan (no extra allocs):
//   d_ws [64MB]: tgtH | tgtL  (until gemm2)  -> attnB | combB (for gemm3)
//   d_out ctx region [64MB]: WH|WL (until gemm1) -> topH | topL (until gemm2)
//   d_out attn region [64MB]: xtH | xtL (until gemm1) -> scores/attn

typedef float    floatx4 __attribute__((ext_vector_type(4)));
typedef short    short8  __attribute__((ext_vector_type(8)));
typedef short    short4v __attribute__((ext_vector_type(4)));
typedef _Float16 half8   __attribute__((ext_vector_type(8)));

constexpr int Bb = 16, Cc = 1024, Tt = 1024, Ss = 1024;
#define SCALE_W 0.70710678118654752440f

__device__ __forceinline__ floatx4 mfma16(short8 a, short8 b, floatx4 c) {
  return __builtin_amdgcn_mfma_f32_16x16x32_f16(
      __builtin_bit_cast(half8, a), __builtin_bit_cast(half8, b), c, 0, 0, 0);
}
__device__ __forceinline__ unsigned short f2fh(float f) {  // RNE
  return __builtin_bit_cast(unsigned short, (_Float16)f);
}
__device__ __forceinline__ float fh2f(unsigned short h) {
  return (float)__builtin_bit_cast(_Float16, h);
}
#define GLDS16(g, l)                                        \
  __builtin_amdgcn_global_load_lds(                         \
      (const __attribute__((address_space(1))) void*)(g),   \
      (__attribute__((address_space(3))) void*)(l), 16, 0, 0)
#define WAIT_VM8 asm volatile("s_waitcnt vmcnt(8)" ::: "memory")
#define WAIT_VM4 asm volatile("s_waitcnt vmcnt(4)" ::: "memory")
#define WAIT_VM0 asm volatile("s_waitcnt vmcnt(0)" ::: "memory")
#define BAR __builtin_amdgcn_s_barrier()
#define SCHEDB __builtin_amdgcn_sched_barrier(0)

// ---------------------------------------------------------------------------
// Elementwise fp32 -> hi/lo fp16 planes (for W).
// ---------------------------------------------------------------------------
__global__ __launch_bounds__(256) void split_kernel(
    const float* __restrict__ in, unsigned short* __restrict__ outH,
    unsigned short* __restrict__ outL) {
  size_t i4 = (size_t)blockIdx.x * 256 + threadIdx.x;
  float4 v = ((const float4*)in)[i4];
  float f[4] = {v.x, v.y, v.z, v.w};
  short4v h, lo;
#pragma unroll
  for (int q = 0; q < 4; ++q) {
    unsigned short hh = f2fh(f[q]);
    h[q] = (short)hh;
    lo[q] = (short)f2fh(f[q] - fh2f(hh));
  }
  *(short4v*)(outH + i4 * 4) = h;
  *(short4v*)(outL + i4 * 4) = lo;
}

// ---------------------------------------------------------------------------
// Elementwise fp32 -> fp16 (for comb).
// ---------------------------------------------------------------------------
__global__ __launch_bounds__(256) void cvt_kernel(
    const float* __restrict__ in, unsigned short* __restrict__ out) {
  size_t i4 = (size_t)blockIdx.x * 256 + threadIdx.x;
  float4 v = ((const float4*)in)[i4];
  short4v h;
  h[0] = (short)f2fh(v.x);
  h[1] = (short)f2fh(v.y);
  h[2] = (short)f2fh(v.z);
  h[3] = (short)f2fh(v.w);
  *(short4v*)(out + i4 * 4) = h;
}

// ---------------------------------------------------------------------------
// Transpose + hi/lo split: in[b][i][j] fp32 -> outH/outL[b][j][i] fp16.
// ---------------------------------------------------------------------------
__global__ __launch_bounds__(256) void transpose_split_kernel(
    const float* __restrict__ in, unsigned short* __restrict__ outH,
    unsigned short* __restrict__ outL) {
  __shared__ float tile[64][65];
  const int b = blockIdx.z;
  const int i0 = blockIdx.y * 64;
  const int j0 = blockIdx.x * 64;
  const int tid = threadIdx.x;
  const float* pin = in + ((size_t)b * 1024 + i0) * 1024 + j0;
#pragma unroll
  for (int it = 0; it < 4; ++it) {
    int e = tid + it * 256;
    int r = e >> 4, ch = e & 15;
    float4 v = *(const float4*)(pin + (size_t)r * 1024 + ch * 4);
    tile[r][ch * 4 + 0] = v.x;
    tile[r][ch * 4 + 1] = v.y;
    tile[r][ch * 4 + 2] = v.z;
    tile[r][ch * 4 + 3] = v.w;
  }
  __syncthreads();
#pragma unroll
  for (int it = 0; it < 4; ++it) {
    int e = tid + it * 256;
    int r = e >> 4, ch = e & 15;  // r: out row (j), ch: out col chunk (i)
    short4v h, lo;
#pragma unroll
    for (int q = 0; q < 4; ++q) {
      float f = tile[ch * 4 + q][r];
      unsigned short hh = f2fh(f);
      h[q] = (short)hh;
      lo[q] = (short)f2fh(f - fh2f(hh));
    }
    size_t o = ((size_t)b * 1024 + j0 + r) * 1024 + i0 + ch * 4;
    *(short4v*)(outH + o) = h;
    *(short4v*)(outL + o) = lo;
  }
}

// ---------------------------------------------------------------------------
// GEMM1 (split x split): tgt[t][d] = SCALE*(base[d][t]+bias[d]+sum_c W[d][c]x[c][t])
// m=d, n=t, k=c.  A=WH/WL [m][k] fp16 (glds).  B=xt hi/lo [n][k] fp16 (glds).
// Counted-vmcnt dbuf: prefetch stays in flight across the barrier.
// ---------------------------------------------------------------------------
__global__ __launch_bounds__(256) void gemm1_kernel(
    const unsigned short* __restrict__ WH, const unsigned short* __restrict__ WL,
    const unsigned short* __restrict__ xH, const unsigned short* __restrict__ xL,
    const float* __restrict__ base, const float* __restrict__ bias,
    unsigned short* __restrict__ tgtH, unsigned short* __restrict__ tgtL) {
  __shared__ alignas(16) short AsH[2][128 * 32], AsL[2][128 * 32];
  __shared__ alignas(16) short BsH[2][128 * 32], BsL[2][128 * 32];
  const int b = blockIdx.z;
  const int m0 = blockIdx.y * 128;  // d
  const int n0 = blockIdx.x * 128;  // t
  const int tid = threadIdx.x;
  const int wid = tid >> 6, l = tid & 63;
  const int wm = (wid >> 1) * 64, wn = (wid & 1) * 64;
  const int quad = l >> 4, l15 = l & 15;
  const int sq8 = (quad ^ ((l15 >> 1) & 3)) * 8;  // swizzled read granule

  floatx4 acc[4][4];
#pragma unroll
  for (int i = 0; i < 4; ++i)
#pragma unroll
    for (int j = 0; j < 4; ++j) acc[i][j] = (floatx4){0.f, 0.f, 0.f, 0.f};

  const size_t aoff = (size_t)m0 * Cc;
  const size_t xoff = ((size_t)b * Tt + n0) * Cc;
  const int rb0 = wid * 32, rb1 = wid * 32 + 16;
  const int lrow = l >> 2;
  const int lcol = (((l & 3) ^ ((lrow >> 1) & 3)) * 8);  // pre-swizzled source

#define STAGE1(kk, bb)                                                          \
  {                                                                             \
    GLDS16(WH + aoff + (size_t)(rb0 + lrow) * Cc + (kk) + lcol, &AsH[bb][rb0 * 32]); \
    GLDS16(WH + aoff + (size_t)(rb1 + lrow) * Cc + (kk) + lcol, &AsH[bb][rb1 * 32]); \
    GLDS16(WL + aoff + (size_t)(rb0 + lrow) * Cc + (kk) + lcol, &AsL[bb][rb0 * 32]); \
    GLDS16(WL + aoff + (size_t)(rb1 + lrow) * Cc + (kk) + lcol, &AsL[bb][rb1 * 32]); \
    GLDS16(xH + xoff + (size_t)(rb0 + lrow) * Cc + (kk) + lcol, &BsH[bb][rb0 * 32]); \
    GLDS16(xH + xoff + (size_t)(rb1 + lrow) * Cc + (kk) + lcol, &BsH[bb][rb1 * 32]); \
    GLDS16(xL + xoff + (size_t)(rb0 + lrow) * Cc + (kk) + lcol, &BsL[bb][rb0 * 32]); \
    GLDS16(xL + xoff + (size_t)(rb1 + lrow) * Cc + (kk) + lcol, &BsL[bb][rb1 * 32]); \
  }

  int cur = 0;
  STAGE1(0, 0);
  for (int k0 = 0; k0 < Cc; k0 += 32) {
    if (k0 + 32 < Cc) {
      STAGE1(k0 + 32, cur ^ 1);
      WAIT_VM8;  // previous tile's 8 loads done; current 8 stay in flight
    } else {
      WAIT_VM0;
    }
    BAR;
    SCHEDB;
    short8 aH[4], aL[4], bH[4], bL[4];
#pragma unroll
    for (int i = 0; i < 4; ++i) {
      aH[i] = *(const short8*)&AsH[cur][(wm + i * 16 + l15) * 32 + sq8];
      aL[i] = *(const short8*)&AsL[cur][(wm + i * 16 + l15) * 32 + sq8];
      bH[i] = *(const short8*)&BsH[cur][(wn + i * 16 + l15) * 32 + sq8];
      bL[i] = *(const short8*)&BsL[cur][(wn + i * 16 + l15) * 32 + sq8];
    }
#pragma unroll
    for (int i = 0; i < 4; ++i)
#pragma unroll
      for (int j = 0; j < 4; ++j) {
        acc[i][j] = mfma16(aH[i], bH[j], acc[i][j]);
        acc[i][j] = mfma16(aH[i], bL[j], acc[i][j]);
        acc[i][j] = mfma16(aL[i], bH[j], acc[i][j]);
      }
    BAR;  // all waves done reading buf[cur] before next iter's STAGE overwrites
    cur ^= 1;
  }
#undef STAGE1
  // Epilogue: + bias + base, scale, split hi/lo, store [t][c]
#pragma unroll
  for (int i = 0; i < 4; ++i) {
    int dbase = m0 + wm + i * 16 + quad * 4;
    float4 bv = *(const float4*)(bias + dbase);
    float bvv[4] = {bv.x, bv.y, bv.z, bv.w};
#pragma unroll
    for (int j = 0; j < 4; ++j) {
      int t = n0 + wn + j * 16 + l15;
      short4v h, lo;
#pragma unroll
      for (int r = 0; r < 4; ++r) {
        float v = (acc[i][j][r] + bvv[r] +
                   base[((size_t)b * Cc + dbase + r) * Tt + t]) * SCALE_W;
        unsigned short hh = f2fh(v);
        h[r] = (short)hh;
        lo[r] = (short)f2fh(v - fh2f(hh));
      }
      size_t o = ((size_t)b * Tt + t) * Cc + dbase;
      *(short4v*)(tgtH + o) = h;
      *(short4v*)(tgtL + o) = lo;
    }
  }
}

// ---------------------------------------------------------------------------
// GEMM2 (split x split): scores[t][s] = sum_c tgt[t][c] top_t[s][c]
// m=t, n=s, k=c.  Counted-vmcnt dbuf as gemm1.
// ---------------------------------------------------------------------------
__global__ __launch_bounds__(256) void gemm2_kernel(
    const unsigned short* __restrict__ tgtH, const unsigned short* __restrict__ tgtL,
    const unsigned short* __restrict__ topH, const unsigned short* __restrict__ topL,
    float* __restrict__ scores) {
  __shared__ alignas(16) short AsH[2][128 * 32], AsL[2][128 * 32];
  __shared__ alignas(16) short BsH[2][128 * 32], BsL[2][128 * 32];
  const int b = blockIdx.z;
  const int t0 = blockIdx.y * 128;  // m
  const int s0 = blockIdx.x * 128;  // n
  const int tid = threadIdx.x;
  const int wid = tid >> 6, l = tid & 63;
  const int wm = (wid >> 1) * 64, wn = (wid & 1) * 64;
  const int quad = l >> 4, l15 = l & 15;
  const int sq8 = (quad ^ ((l15 >> 1) & 3)) * 8;

  floatx4 acc[4][4];
#pragma unroll
  for (int i = 0; i < 4; ++i)
#pragma unroll
    for (int j = 0; j < 4; ++j) acc[i][j] = (floatx4){0.f, 0.f, 0.f, 0.f};

  const size_t aoff = ((size_t)b * Tt + t0) * Cc;
  const size_t boff = ((size_t)b * Ss + s0) * Cc;
  const int rb0 = wid * 32, rb1 = wid * 32 + 16;
  const int lrow = l >> 2;
  const int lcol = (((l & 3) ^ ((lrow >> 1) & 3)) * 8);

#define STAGE2(kk, bb)                                                          \
  {                                                                             \
    GLDS16(tgtH + aoff + (size_t)(rb0 + lrow) * Cc + (kk) + lcol, &AsH[bb][rb0 * 32]); \
    GLDS16(tgtH + aoff + (size_t)(rb1 + lrow) * Cc + (kk) + lcol, &AsH[bb][rb1 * 32]); \
    GLDS16(tgtL + aoff + (size_t)(rb0 + lrow) * Cc + (kk) + lcol, &AsL[bb][rb0 * 32]); \
    GLDS16(tgtL + aoff + (size_t)(rb1 + lrow) * Cc + (kk) + lcol, &AsL[bb][rb1 * 32]); \
    GLDS16(topH + boff + (size_t)(rb0 + lrow) * Cc + (kk) + lcol, &BsH[bb][rb0 * 32]); \
    GLDS16(topH + boff + (size_t)(rb1 + lrow) * Cc + (kk) + lcol, &BsH[bb][rb1 * 32]); \
    GLDS16(topL + boff + (size_t)(rb0 + lrow) * Cc + (kk) + lcol, &BsL[bb][rb0 * 32]); \
    GLDS16(topL + boff + (size_t)(rb1 + lrow) * Cc + (kk) + lcol, &BsL[bb][rb1 * 32]); \
  }

  int cur = 0;
  STAGE2(0, 0);
  for (int k0 = 0; k0 < Cc; k0 += 32) {
    if (k0 + 32 < Cc) {
      STAGE2(k0 + 32, cur ^ 1);
      WAIT_VM8;
    } else {
      WAIT_VM0;
    }
    BAR;
    SCHEDB;
    short8 aH[4], aL[4], bH[4], bL[4];
#pragma unroll
    for (int i = 0; i < 4; ++i) {
      aH[i] = *(const short8*)&AsH[cur][(wm + i * 16 + l15) * 32 + sq8];
      aL[i] = *(const short8*)&AsL[cur][(wm + i * 16 + l15) * 32 + sq8];
      bH[i] = *(const short8*)&BsH[cur][(wn + i * 16 + l15) * 32 + sq8];
      bL[i] = *(const short8*)&BsL[cur][(wn + i * 16 + l15) * 32 + sq8];
    }
#pragma unroll
    for (int i = 0; i < 4; ++i)
#pragma unroll
      for (int j = 0; j < 4; ++j) {
        acc[i][j] = mfma16(aH[i], bH[j], acc[i][j]);
        acc[i][j] = mfma16(aH[i], bL[j], acc[i][j]);
        acc[i][j] = mfma16(aL[i], bH[j], acc[i][j]);
      }
    BAR;
    cur ^= 1;
  }
#undef STAGE2
#pragma unroll
  for (int i = 0; i < 4; ++i)
#pragma unroll
    for (int j = 0; j < 4; ++j) {
      int s_ = s0 + wn + j * 16 + l15;
#pragma unroll
      for (int r = 0; r < 4; ++r) {
        int t_ = t0 + wm + i * 16 + quad * 4 + r;
        scores[((size_t)b * Tt + t_) * Ss + s_] = acc[i][j][r];
      }
    }
}

// ---------------------------------------------------------------------------
// Softmax over S=1024, one block per row, in place (fp32) + fp16 copy out.
// ---------------------------------------------------------------------------
__global__ __launch_bounds__(256) void softmax_kernel(
    float* __restrict__ attn, unsigned short* __restrict__ attnB) {
  __shared__ float red[8];
  float* p = attn + (size_t)blockIdx.x * Ss;
  const int tid = threadIdx.x;
  float4 v = *(float4*)(p + tid * 4);
  float m = fmaxf(fmaxf(v.x, v.y), fmaxf(v.z, v.w));
#pragma unroll
  for (int off = 1; off < 64; off <<= 1) m = fmaxf(m, __shfl_xor(m, off));
  const int wave = tid >> 6, lane = tid & 63;
  if (lane == 0) red[wave] = m;
  __syncthreads();
  m = fmaxf(fmaxf(red[0], red[1]), fmaxf(red[2], red[3]));
  v.x = __expf(v.x - m);
  v.y = __expf(v.y - m);
  v.z = __expf(v.z - m);
  v.w = __expf(v.w - m);
  float s = v.x + v.y + v.z + v.w;
#pragma unroll
  for (int off = 1; off < 64; off <<= 1) s += __shfl_xor(s, off);
  if (lane == 0) red[4 + wave] = s;
  __syncthreads();
  s = red[4] + red[5] + red[6] + red[7];
  float inv = 1.0f / s;
  v.x *= inv;
  v.y *= inv;
  v.z *= inv;
  v.w *= inv;
  *(float4*)(p + tid * 4) = v;
  short4v h;
  h[0] = (short)f2fh(v.x);
  h[1] = (short)f2fh(v.y);
  h[2] = (short)f2fh(v.z);
  h[3] = (short)f2fh(v.w);
  *(short4v*)(attnB + (size_t)blockIdx.x * Ss + tid * 4) = h;
}

// ---------------------------------------------------------------------------
// GEMM3 (plain fp16): ctx[c][t] = sum_s comb[c][s] attn[t][s]
// m=c, n=t, k=s.  Counted-vmcnt dbuf (4 loads/step -> vmcnt(4)).
// ---------------------------------------------------------------------------
__global__ __launch_bounds__(256) void gemm3_kernel(
    const unsigned short* __restrict__ combB,
    const unsigned short* __restrict__ attnB, float* __restrict__ ctx) {
  __shared__ alignas(16) short As[2][128 * 32], Bs[2][128 * 32];
  const int b = blockIdx.z;
  const int m0 = blockIdx.y * 128;  // c
  const int n0 = blockIdx.x * 128;  // t
  const int tid = threadIdx.x;
  const int wid = tid >> 6, l = tid & 63;
  const int wm = (wid >> 1) * 64, wn = (wid & 1) * 64;
  const int quad = l >> 4, l15 = l & 15;
  const int sq8 = (quad ^ ((l15 >> 1) & 3)) * 8;

  floatx4 acc[4][4];
#pragma unroll
  for (int i = 0; i < 4; ++i)
#pragma unroll
    for (int j = 0; j < 4; ++j) acc[i][j] = (floatx4){0.f, 0.f, 0.f, 0.f};

  const size_t aoff = ((size_t)b * Cc + m0) * Ss;
  const size_t boff = ((size_t)b * Tt + n0) * Ss;
  const int rb0 = wid * 32, rb1 = wid * 32 + 16;
  const int lrow = l >> 2;
  const int lcol = (((l & 3) ^ ((lrow >> 1) & 3)) * 8);

#define STAGE3(kk, bb)                                                          \
  {                                                                             \
    GLDS16(combB + aoff + (size_t)(rb0 + lrow) * Ss + (kk) + lcol, &As[bb][rb0 * 32]); \
    GLDS16(combB + aoff + (size_t)(rb1 + lrow) * Ss + (kk) + lcol, &As[bb][rb1 * 32]); \
    GLDS16(attnB + boff + (size_t)(rb0 + lrow) * Ss + (kk) + lcol, &Bs[bb][rb0 * 32]); \
    GLDS16(attnB + boff + (size_t)(rb1 + lrow) * Ss + (kk) + lcol, &Bs[bb][rb1 * 32]); \
  }

  int cur = 0;
  STAGE3(0, 0);
  for (int k0 = 0; k0 < Ss; k0 += 32) {
    if (k0 + 32 < Ss) {
      STAGE3(k0 + 32, cur ^ 1);
      WAIT_VM4;
    } else {
      WAIT_VM0;
    }
    BAR;
    SCHEDB;
    short8 af[4], bf[4];
#pragma unroll
    for (int i = 0; i < 4; ++i) {
      af[i] = *(const short8*)&As[cur][(wm + i * 16 + l15) * 32 + sq8];
      bf[i] = *(const short8*)&Bs[cur][(wn + i * 16 + l15) * 32 + sq8];
    }
#pragma unroll
    for (int i = 0; i < 4; ++i)
#pragma unroll
      for (int j = 0; j < 4; ++j) acc[i][j] = mfma16(af[i], bf[j], acc[i][j]);
    BAR;
    cur ^= 1;
  }
#undef STAGE3
#pragma unroll
  for (int i = 0; i < 4; ++i)
#pragma unroll
    for (int j = 0; j < 4; ++j) {
      int t_ = n0 + wn + j * 16 + l15;
#pragma unroll
      for (int r = 0; r < 4; ++r) {
        int c_ = m0 + wm + i * 16 + quad * 4 + r;
        ctx[((size_t)b * Cc + c_) * Tt + t_] = acc[i][j][r];
      }
    }
}

extern "C" void kernel_launch(void* const* d_in, const int* in_sizes, int n_in,
                              void* d_out, int out_size, void* d_ws,
                              size_t ws_size, hipStream_t stream) {
  const float* base = (const float*)d_in[0];  // [B,C,T]
  const float* x = (const float*)d_in[1];     // [B,C,T]
  const float* top = (const float*)d_in[2];   // [B,C,S]
  const float* comb = (const float*)d_in[3];  // [B,C,S]
  const float* W = (const float*)d_in[4];     // [C,C]
  const float* bias = (const float*)d_in[5];  // [C]

  const size_t NE = (size_t)Bb * 1024 * 1024;  // 16M elements per plane
  float* ctx_out = (float*)d_out;              // [B,C,T]
  float* attn = (float*)d_out + NE;            // [B,T,S]
  // temp planes in dead regions:
  unsigned short* WH = (unsigned short*)d_out;  // ctx region, until gemm1 done
  unsigned short* WL = WH + (size_t)Cc * Cc;
  unsigned short* topH = (unsigned short*)d_out;  // ctx region, until gemm3
  unsigned short* topL = topH + NE;
  unsigned short* xtH = (unsigned short*)attn;  // attn region, until gemm2
  unsigned short* xtL = xtH + NE;
  unsigned short* tgtH = (unsigned short*)d_ws;  // ws, until gemm2 done
  unsigned short* tgtL = tgtH + NE;
  unsigned short* attnB = (unsigned short*)d_ws;  // ws reuse after gemm2
  unsigned short* combB = attnB + NE;

  dim3 blk(256);
  // 1. W -> WH/WL (ctx region; consumed by gemm1 before top transpose)
  split_kernel<<<dim3((Cc * Cc) / 1024), blk, 0, stream>>>(W, WH, WL);
  // 2. x -> xt planes (attn region)
  transpose_split_kernel<<<dim3(16, 16, Bb), blk, 0, stream>>>(x, xtH, xtL);
  // 3. gemm1 -> tgt planes (ws)
  gemm1_kernel<<<dim3(Tt / 128, Cc / 128, Bb), blk, 0, stream>>>(
      WH, WL, xtH, xtL, base, bias, tgtH, tgtL);
  // 4. top -> top planes (ctx region; overwrites WH/WL, now dead)
  transpose_split_kernel<<<dim3(16, 16, Bb), blk, 0, stream>>>(top, topH, topL);
  // 5. gemm2 -> scores (attn region; overwrites xt planes, now dead)
  gemm2_kernel<<<dim3(Ss / 128, Tt / 128, Bb), blk, 0, stream>>>(
      tgtH, tgtL, topH, topL, attn);
  // 6. softmax in place + fp16 copy into ws (tgt planes now dead)
  softmax_kernel<<<dim3(Bb * Tt), blk, 0, stream>>>(attn, attnB);
  // 7. comb -> fp16 (ws second half)
  cvt_kernel<<<dim3(NE / 1024), blk, 0, stream>>>(comb, combB);
  // 8. gemm3 -> ctx (overwrites top planes, now dead)
  gemm3_kernel<<<dim3(Tt / 128, Cc / 128, Bb), blk, 0, stream>>>(
      combB, attnB, ctx_out);
}

// Round 4
// 598.799 us; speedup vs baseline: 1.0731x; 1.0731x over previous
//
#include <hip/hip_runtime.h>

// ConvMultiStepAttention, B=16, C=T=S=1024, fp32 in/out.
// R6: 2-product split (precision-margin spend, structure unchanged from R5):
//   gemm1: tgt = (WH+WL)·xH  (x hi-only; tgt stored hi-only)
//   gemm2: scores = tgtH·(topH+topL)
//   Error model: logit err ~0.011 RMS (vs sigma=32), attn shift <=~0.005.
//   MFMA/step 48->32, LDS reads 16->12, glds 8->6, LDS 64->48KB (3 blocks/CU).
// Buffer plan (no extra allocs):
//   d_ws [64MB]: tgtH (until gemm2) -> attnB | combB (for gemm3)
//   d_out ctx region [64MB]: WH|WL (until gemm1) -> topH|topL (until gemm3)
//   d_out attn region [64MB]: xtH (until gemm2) -> scores/attn

typedef float    floatx4 __attribute__((ext_vector_type(4)));
typedef short    short8  __attribute__((ext_vector_type(8)));
typedef short    short4v __attribute__((ext_vector_type(4)));
typedef _Float16 half8   __attribute__((ext_vector_type(8)));

constexpr int Bb = 16, Cc = 1024, Tt = 1024, Ss = 1024;
#define SCALE_W 0.70710678118654752440f

__device__ __forceinline__ floatx4 mfma16(short8 a, short8 b, floatx4 c) {
  return __builtin_amdgcn_mfma_f32_16x16x32_f16(
      __builtin_bit_cast(half8, a), __builtin_bit_cast(half8, b), c, 0, 0, 0);
}
__device__ __forceinline__ unsigned short f2fh(float f) {  // RNE
  return __builtin_bit_cast(unsigned short, (_Float16)f);
}
__device__ __forceinline__ float fh2f(unsigned short h) {
  return (float)__builtin_bit_cast(_Float16, h);
}
#define GLDS16(g, l)                                        \
  __builtin_amdgcn_global_load_lds(                         \
      (const __attribute__((address_space(1))) void*)(g),   \
      (__attribute__((address_space(3))) void*)(l), 16, 0, 0)
#define WAIT_VM6 asm volatile("s_waitcnt vmcnt(6)" ::: "memory")
#define WAIT_VM4 asm volatile("s_waitcnt vmcnt(4)" ::: "memory")
#define WAIT_VM0 asm volatile("s_waitcnt vmcnt(0)" ::: "memory")
#define BAR __builtin_amdgcn_s_barrier()
#define SCHEDB __builtin_amdgcn_sched_barrier(0)

// ---------------------------------------------------------------------------
// Elementwise fp32 -> hi/lo fp16 planes (for W).
// ---------------------------------------------------------------------------
__global__ __launch_bounds__(256) void split_kernel(
    const float* __restrict__ in, unsigned short* __restrict__ outH,
    unsigned short* __restrict__ outL) {
  size_t i4 = (size_t)blockIdx.x * 256 + threadIdx.x;
  float4 v = ((const float4*)in)[i4];
  float f[4] = {v.x, v.y, v.z, v.w};
  short4v h, lo;
#pragma unroll
  for (int q = 0; q < 4; ++q) {
    unsigned short hh = f2fh(f[q]);
    h[q] = (short)hh;
    lo[q] = (short)f2fh(f[q] - fh2f(hh));
  }
  *(short4v*)(outH + i4 * 4) = h;
  *(short4v*)(outL + i4 * 4) = lo;
}

// ---------------------------------------------------------------------------
// Elementwise fp32 -> fp16 (for comb).
// ---------------------------------------------------------------------------
__global__ __launch_bounds__(256) void cvt_kernel(
    const float* __restrict__ in, unsigned short* __restrict__ out) {
  size_t i4 = (size_t)blockIdx.x * 256 + threadIdx.x;
  float4 v = ((const float4*)in)[i4];
  short4v h;
  h[0] = (short)f2fh(v.x);
  h[1] = (short)f2fh(v.y);
  h[2] = (short)f2fh(v.z);
  h[3] = (short)f2fh(v.w);
  *(short4v*)(out + i4 * 4) = h;
}

// ---------------------------------------------------------------------------
// Transpose + hi/lo split: in[b][i][j] fp32 -> outH/outL[b][j][i] fp16.
// ---------------------------------------------------------------------------
__global__ __launch_bounds__(256) void transpose_split_kernel(
    const float* __restrict__ in, unsigned short* __restrict__ outH,
    unsigned short* __restrict__ outL) {
  __shared__ float tile[64][65];
  const int b = blockIdx.z;
  const int i0 = blockIdx.y * 64;
  const int j0 = blockIdx.x * 64;
  const int tid = threadIdx.x;
  const float* pin = in + ((size_t)b * 1024 + i0) * 1024 + j0;
#pragma unroll
  for (int it = 0; it < 4; ++it) {
    int e = tid + it * 256;
    int r = e >> 4, ch = e & 15;
    float4 v = *(const float4*)(pin + (size_t)r * 1024 + ch * 4);
    tile[r][ch * 4 + 0] = v.x;
    tile[r][ch * 4 + 1] = v.y;
    tile[r][ch * 4 + 2] = v.z;
    tile[r][ch * 4 + 3] = v.w;
  }
  __syncthreads();
#pragma unroll
  for (int it = 0; it < 4; ++it) {
    int e = tid + it * 256;
    int r = e >> 4, ch = e & 15;  // r: out row (j), ch: out col chunk (i)
    short4v h, lo;
#pragma unroll
    for (int q = 0; q < 4; ++q) {
      float f = tile[ch * 4 + q][r];
      unsigned short hh = f2fh(f);
      h[q] = (short)hh;
      lo[q] = (short)f2fh(f - fh2f(hh));
    }
    size_t o = ((size_t)b * 1024 + j0 + r) * 1024 + i0 + ch * 4;
    *(short4v*)(outH + o) = h;
    *(short4v*)(outL + o) = lo;
  }
}

// ---------------------------------------------------------------------------
// Transpose hi-only: in[b][i][j] fp32 -> outH[b][j][i] fp16 (for x).
// ---------------------------------------------------------------------------
__global__ __launch_bounds__(256) void transpose_h_kernel(
    const float* __restrict__ in, unsigned short* __restrict__ outH) {
  __shared__ float tile[64][65];
  const int b = blockIdx.z;
  const int i0 = blockIdx.y * 64;
  const int j0 = blockIdx.x * 64;
  const int tid = threadIdx.x;
  const float* pin = in + ((size_t)b * 1024 + i0) * 1024 + j0;
#pragma unroll
  for (int it = 0; it < 4; ++it) {
    int e = tid + it * 256;
    int r = e >> 4, ch = e & 15;
    float4 v = *(const float4*)(pin + (size_t)r * 1024 + ch * 4);
    tile[r][ch * 4 + 0] = v.x;
    tile[r][ch * 4 + 1] = v.y;
    tile[r][ch * 4 + 2] = v.z;
    tile[r][ch * 4 + 3] = v.w;
  }
  __syncthreads();
#pragma unroll
  for (int it = 0; it < 4; ++it) {
    int e = tid + it * 256;
    int r = e >> 4, ch = e & 15;
    short4v h;
#pragma unroll
    for (int q = 0; q < 4; ++q) h[q] = (short)f2fh(tile[ch * 4 + q][r]);
    size_t o = ((size_t)b * 1024 + j0 + r) * 1024 + i0 + ch * 4;
    *(short4v*)(outH + o) = h;
  }
}

// ---------------------------------------------------------------------------
// GEMM1 (2-product): tgt[t][d] = SCALE*(base[d][t]+bias[d]+sum_c W[d][c]x[c][t])
// m=d, n=t, k=c.  A=WH/WL [m][k] fp16 (glds).  B=xtH [n][k] fp16 (glds).
// tgt = (WH+WL)*xH; output stored hi-only.
// ---------------------------------------------------------------------------
__global__ __launch_bounds__(256) void gemm1_kernel(
    const unsigned short* __restrict__ WH, const unsigned short* __restrict__ WL,
    const unsigned short* __restrict__ xH, const float* __restrict__ base,
    const float* __restrict__ bias, unsigned short* __restrict__ tgtH) {
  __shared__ alignas(16) short AsH[2][128 * 32], AsL[2][128 * 32];
  __shared__ alignas(16) short Bs[2][128 * 32];
  const int b = blockIdx.z;
  const int m0 = blockIdx.y * 128;  // d
  const int n0 = blockIdx.x * 128;  // t
  const int tid = threadIdx.x;
  const int wid = tid >> 6, l = tid & 63;
  const int wm = (wid >> 1) * 64, wn = (wid & 1) * 64;
  const int quad = l >> 4, l15 = l & 15;
  const int sq8 = (quad ^ ((l15 >> 1) & 3)) * 8;  // swizzled read granule

  floatx4 acc[4][4];
#pragma unroll
  for (int i = 0; i < 4; ++i)
#pragma unroll
    for (int j = 0; j < 4; ++j) acc[i][j] = (floatx4){0.f, 0.f, 0.f, 0.f};

  const size_t aoff = (size_t)m0 * Cc;
  const size_t xoff = ((size_t)b * Tt + n0) * Cc;
  const int rb0 = wid * 32, rb1 = wid * 32 + 16;
  const int lrow = l >> 2;
  const int lcol = (((l & 3) ^ ((lrow >> 1) & 3)) * 8);  // pre-swizzled source

#define STAGE1(kk, bb)                                                          \
  {                                                                             \
    GLDS16(WH + aoff + (size_t)(rb0 + lrow) * Cc + (kk) + lcol, &AsH[bb][rb0 * 32]); \
    GLDS16(WH + aoff + (size_t)(rb1 + lrow) * Cc + (kk) + lcol, &AsH[bb][rb1 * 32]); \
    GLDS16(WL + aoff + (size_t)(rb0 + lrow) * Cc + (kk) + lcol, &AsL[bb][rb0 * 32]); \
    GLDS16(WL + aoff + (size_t)(rb1 + lrow) * Cc + (kk) + lcol, &AsL[bb][rb1 * 32]); \
    GLDS16(xH + xoff + (size_t)(rb0 + lrow) * Cc + (kk) + lcol, &Bs[bb][rb0 * 32]); \
    GLDS16(xH + xoff + (size_t)(rb1 + lrow) * Cc + (kk) + lcol, &Bs[bb][rb1 * 32]); \
  }

  int cur = 0;
  STAGE1(0, 0);
  for (int k0 = 0; k0 < Cc; k0 += 32) {
    if (k0 + 32 < Cc) {
      STAGE1(k0 + 32, cur ^ 1);
      WAIT_VM6;  // previous tile's 6 loads done; current 6 stay in flight
    } else {
      WAIT_VM0;
    }
    BAR;
    SCHEDB;
    short8 aH[4], aL[4], bf[4];
#pragma unroll
    for (int i = 0; i < 4; ++i) {
      aH[i] = *(const short8*)&AsH[cur][(wm + i * 16 + l15) * 32 + sq8];
      aL[i] = *(const short8*)&AsL[cur][(wm + i * 16 + l15) * 32 + sq8];
      bf[i] = *(const short8*)&Bs[cur][(wn + i * 16 + l15) * 32 + sq8];
    }
#pragma unroll
    for (int i = 0; i < 4; ++i)
#pragma unroll
      for (int j = 0; j < 4; ++j) {
        acc[i][j] = mfma16(aH[i], bf[j], acc[i][j]);
        acc[i][j] = mfma16(aL[i], bf[j], acc[i][j]);
      }
    BAR;  // all waves done reading buf[cur] before next iter's STAGE overwrites
    cur ^= 1;
  }
#undef STAGE1
  // Epilogue: + bias + base, scale, store hi plane [t][c]
#pragma unroll
  for (int i = 0; i < 4; ++i) {
    int dbase = m0 + wm + i * 16 + quad * 4;
    float4 bv = *(const float4*)(bias + dbase);
    float bvv[4] = {bv.x, bv.y, bv.z, bv.w};
#pragma unroll
    for (int j = 0; j < 4; ++j) {
      int t = n0 + wn + j * 16 + l15;
      short4v h;
#pragma unroll
      for (int r = 0; r < 4; ++r) {
        float v = (acc[i][j][r] + bvv[r] +
                   base[((size_t)b * Cc + dbase + r) * Tt + t]) * SCALE_W;
        h[r] = (short)f2fh(v);
      }
      size_t o = ((size_t)b * Tt + t) * Cc + dbase;
      *(short4v*)(tgtH + o) = h;
    }
  }
}

// ---------------------------------------------------------------------------
// GEMM2 (2-product): scores[t][s] = sum_c tgt[t][c] top_t[s][c]
// m=t, n=s, k=c.  A=tgtH [t][c]; B=topH/topL [s][c].  scores = tgtH*(topH+topL).
// ---------------------------------------------------------------------------
__global__ __launch_bounds__(256) void gemm2_kernel(
    const unsigned short* __restrict__ tgtH,
    const unsigned short* __restrict__ topH, const unsigned short* __restrict__ topL,
    float* __restrict__ scores) {
  __shared__ alignas(16) short As[2][128 * 32];
  __shared__ alignas(16) short BsH[2][128 * 32], BsL[2][128 * 32];
  const int b = blockIdx.z;
  const int t0 = blockIdx.y * 128;  // m
  const int s0 = blockIdx.x * 128;  // n
  const int tid = threadIdx.x;
  const int wid = tid >> 6, l = tid & 63;
  const int wm = (wid >> 1) * 64, wn = (wid & 1) * 64;
  const int quad = l >> 4, l15 = l & 15;
  const int sq8 = (quad ^ ((l15 >> 1) & 3)) * 8;

  floatx4 acc[4][4];
#pragma unroll
  for (int i = 0; i < 4; ++i)
#pragma unroll
    for (int j = 0; j < 4; ++j) acc[i][j] = (floatx4){0.f, 0.f, 0.f, 0.f};

  const size_t aoff = ((size_t)b * Tt + t0) * Cc;
  const size_t boff = ((size_t)b * Ss + s0) * Cc;
  const int rb0 = wid * 32, rb1 = wid * 32 + 16;
  const int lrow = l >> 2;
  const int lcol = (((l & 3) ^ ((lrow >> 1) & 3)) * 8);

#define STAGE2(kk, bb)                                                          \
  {                                                                             \
    GLDS16(tgtH + aoff + (size_t)(rb0 + lrow) * Cc + (kk) + lcol, &As[bb][rb0 * 32]); \
    GLDS16(tgtH + aoff + (size_t)(rb1 + lrow) * Cc + (kk) + lcol, &As[bb][rb1 * 32]); \
    GLDS16(topH + boff + (size_t)(rb0 + lrow) * Cc + (kk) + lcol, &BsH[bb][rb0 * 32]); \
    GLDS16(topH + boff + (size_t)(rb1 + lrow) * Cc + (kk) + lcol, &BsH[bb][rb1 * 32]); \
    GLDS16(topL + boff + (size_t)(rb0 + lrow) * Cc + (kk) + lcol, &BsL[bb][rb0 * 32]); \
    GLDS16(topL + boff + (size_t)(rb1 + lrow) * Cc + (kk) + lcol, &BsL[bb][rb1 * 32]); \
  }

  int cur = 0;
  STAGE2(0, 0);
  for (int k0 = 0; k0 < Cc; k0 += 32) {
    if (k0 + 32 < Cc) {
      STAGE2(k0 + 32, cur ^ 1);
      WAIT_VM6;
    } else {
      WAIT_VM0;
    }
    BAR;
    SCHEDB;
    short8 af[4], bH[4], bL[4];
#pragma unroll
    for (int i = 0; i < 4; ++i) {
      af[i] = *(const short8*)&As[cur][(wm + i * 16 + l15) * 32 + sq8];
      bH[i] = *(const short8*)&BsH[cur][(wn + i * 16 + l15) * 32 + sq8];
      bL[i] = *(const short8*)&BsL[cur][(wn + i * 16 + l15) * 32 + sq8];
    }
#pragma unroll
    for (int i = 0; i < 4; ++i)
#pragma unroll
      for (int j = 0; j < 4; ++j) {
        acc[i][j] = mfma16(af[i], bH[j], acc[i][j]);
        acc[i][j] = mfma16(af[i], bL[j], acc[i][j]);
      }
    BAR;
    cur ^= 1;
  }
#undef STAGE2
#pragma unroll
  for (int i = 0; i < 4; ++i)
#pragma unroll
    for (int j = 0; j < 4; ++j) {
      int s_ = s0 + wn + j * 16 + l15;
#pragma unroll
      for (int r = 0; r < 4; ++r) {
        int t_ = t0 + wm + i * 16 + quad * 4 + r;
        scores[((size_t)b * Tt + t_) * Ss + s_] = acc[i][j][r];
      }
    }
}

// ---------------------------------------------------------------------------
// Softmax over S=1024, one block per row, in place (fp32) + fp16 copy out.
// ---------------------------------------------------------------------------
__global__ __launch_bounds__(256) void softmax_kernel(
    float* __restrict__ attn, unsigned short* __restrict__ attnB) {
  __shared__ float red[8];
  float* p = attn + (size_t)blockIdx.x * Ss;
  const int tid = threadIdx.x;
  float4 v = *(float4*)(p + tid * 4);
  float m = fmaxf(fmaxf(v.x, v.y), fmaxf(v.z, v.w));
#pragma unroll
  for (int off = 1; off < 64; off <<= 1) m = fmaxf(m, __shfl_xor(m, off));
  const int wave = tid >> 6, lane = tid & 63;
  if (lane == 0) red[wave] = m;
  __syncthreads();
  m = fmaxf(fmaxf(red[0], red[1]), fmaxf(red[2], red[3]));
  v.x = __expf(v.x - m);
  v.y = __expf(v.y - m);
  v.z = __expf(v.z - m);
  v.w = __expf(v.w - m);
  float s = v.x + v.y + v.z + v.w;
#pragma unroll
  for (int off = 1; off < 64; off <<= 1) s += __shfl_xor(s, off);
  if (lane == 0) red[4 + wave] = s;
  __syncthreads();
  s = red[4] + red[5] + red[6] + red[7];
  float inv = 1.0f / s;
  v.x *= inv;
  v.y *= inv;
  v.z *= inv;
  v.w *= inv;
  *(float4*)(p + tid * 4) = v;
  short4v h;
  h[0] = (short)f2fh(v.x);
  h[1] = (short)f2fh(v.y);
  h[2] = (short)f2fh(v.z);
  h[3] = (short)f2fh(v.w);
  *(short4v*)(attnB + (size_t)blockIdx.x * Ss + tid * 4) = h;
}

// ---------------------------------------------------------------------------
// GEMM3 (plain fp16): ctx[c][t] = sum_s comb[c][s] attn[t][s]
// m=c, n=t, k=s.  Counted-vmcnt dbuf (4 loads/step -> vmcnt(4)).
// ---------------------------------------------------------------------------
__global__ __launch_bounds__(256) void gemm3_kernel(
    const unsigned short* __restrict__ combB,
    const unsigned short* __restrict__ attnB, float* __restrict__ ctx) {
  __shared__ alignas(16) short As[2][128 * 32], Bs[2][128 * 32];
  const int b = blockIdx.z;
  const int m0 = blockIdx.y * 128;  // c
  const int n0 = blockIdx.x * 128;  // t
  const int tid = threadIdx.x;
  const int wid = tid >> 6, l = tid & 63;
  const int wm = (wid >> 1) * 64, wn = (wid & 1) * 64;
  const int quad = l >> 4, l15 = l & 15;
  const int sq8 = (quad ^ ((l15 >> 1) & 3)) * 8;

  floatx4 acc[4][4];
#pragma unroll
  for (int i = 0; i < 4; ++i)
#pragma unroll
    for (int j = 0; j < 4; ++j) acc[i][j] = (floatx4){0.f, 0.f, 0.f, 0.f};

  const size_t aoff = ((size_t)b * Cc + m0) * Ss;
  const size_t boff = ((size_t)b * Tt + n0) * Ss;
  const int rb0 = wid * 32, rb1 = wid * 32 + 16;
  const int lrow = l >> 2;
  const int lcol = (((l & 3) ^ ((lrow >> 1) & 3)) * 8);

#define STAGE3(kk, bb)                                                          \
  {                                                                             \
    GLDS16(combB + aoff + (size_t)(rb0 + lrow) * Ss + (kk) + lcol, &As[bb][rb0 * 32]); \
    GLDS16(combB + aoff + (size_t)(rb1 + lrow) * Ss + (kk) + lcol, &As[bb][rb1 * 32]); \
    GLDS16(attnB + boff + (size_t)(rb0 + lrow) * Ss + (kk) + lcol, &Bs[bb][rb0 * 32]); \
    GLDS16(attnB + boff + (size_t)(rb1 + lrow) * Ss + (kk) + lcol, &Bs[bb][rb1 * 32]); \
  }

  int cur = 0;
  STAGE3(0, 0);
  for (int k0 = 0; k0 < Ss; k0 += 32) {
    if (k0 + 32 < Ss) {
      STAGE3(k0 + 32, cur ^ 1);
      WAIT_VM4;
    } else {
      WAIT_VM0;
    }
    BAR;
    SCHEDB;
    short8 af[4], bf[4];
#pragma unroll
    for (int i = 0; i < 4; ++i) {
      af[i] = *(const short8*)&As[cur][(wm + i * 16 + l15) * 32 + sq8];
      bf[i] = *(const short8*)&Bs[cur][(wn + i * 16 + l15) * 32 + sq8];
    }
#pragma unroll
    for (int i = 0; i < 4; ++i)
#pragma unroll
      for (int j = 0; j < 4; ++j) acc[i][j] = mfma16(af[i], bf[j], acc[i][j]);
    BAR;
    cur ^= 1;
  }
#undef STAGE3
#pragma unroll
  for (int i = 0; i < 4; ++i)
#pragma unroll
    for (int j = 0; j < 4; ++j) {
      int t_ = n0 + wn + j * 16 + l15;
#pragma unroll
      for (int r = 0; r < 4; ++r) {
        int c_ = m0 + wm + i * 16 + quad * 4 + r;
        ctx[((size_t)b * Cc + c_) * Tt + t_] = acc[i][j][r];
      }
    }
}

extern "C" void kernel_launch(void* const* d_in, const int* in_sizes, int n_in,
                              void* d_out, int out_size, void* d_ws,
                              size_t ws_size, hipStream_t stream) {
  const float* base = (const float*)d_in[0];  // [B,C,T]
  const float* x = (const float*)d_in[1];     // [B,C,T]
  const float* top = (const float*)d_in[2];   // [B,C,S]
  const float* comb = (const float*)d_in[3];  // [B,C,S]
  const float* W = (const float*)d_in[4];     // [C,C]
  const float* bias = (const float*)d_in[5];  // [C]

  const size_t NE = (size_t)Bb * 1024 * 1024;  // 16M elements per plane
  float* ctx_out = (float*)d_out;              // [B,C,T]
  float* attn = (float*)d_out + NE;            // [B,T,S]
  // temp planes in dead regions:
  unsigned short* WH = (unsigned short*)d_out;  // ctx region, until gemm1 done
  unsigned short* WL = WH + (size_t)Cc * Cc;
  unsigned short* topH = (unsigned short*)d_out;  // ctx region, until gemm3
  unsigned short* topL = topH + NE;
  unsigned short* xtH = (unsigned short*)attn;  // attn region, until gemm2
  unsigned short* tgtH = (unsigned short*)d_ws;  // ws, until gemm2 done
  unsigned short* attnB = (unsigned short*)d_ws;  // ws reuse after gemm2
  unsigned short* combB = attnB + NE;

  dim3 blk(256);
  // 1. W -> WH/WL (ctx region; consumed by gemm1 before top transpose)
  split_kernel<<<dim3((Cc * Cc) / 1024), blk, 0, stream>>>(W, WH, WL);
  // 2. x -> xtH (attn region)
  transpose_h_kernel<<<dim3(16, 16, Bb), blk, 0, stream>>>(x, xtH);
  // 3. gemm1 -> tgtH (ws)
  gemm1_kernel<<<dim3(Tt / 128, Cc / 128, Bb), blk, 0, stream>>>(
      WH, WL, xtH, base, bias, tgtH);
  // 4. top -> top planes (ctx region; overwrites WH/WL, now dead)
  transpose_split_kernel<<<dim3(16, 16, Bb), blk, 0, stream>>>(top, topH, topL);
  // 5. gemm2 -> scores (attn region; overwrites xtH, now dead)
  gemm2_kernel<<<dim3(Ss / 128, Tt / 128, Bb), blk, 0, stream>>>(
      tgtH, topH, topL, attn);
  // 6. softmax in place + fp16 copy into ws (tgtH now dead)
  softmax_kernel<<<dim3(Bb * Tt), blk, 0, stream>>>(attn, attnB);
  // 7. comb -> fp16 (ws second half)
  cvt_kernel<<<dim3(NE / 1024), blk, 0, stream>>>(comb, combB);
  // 8. gemm3 -> ctx (overwrites top planes, now dead)
  gemm3_kernel<<<dim3(Tt / 128, Cc / 128, Bb), blk, 0, stream>>>(
      combB, attnB, ctx_out);
}

// Round 5
// 552.911 us; speedup vs baseline: 1.1621x; 1.0830x over previous
//
#include <hip/hip_runtime.h>

// ConvMultiStepAttention, B=16, C=T=S=1024, fp32 in/out.
// R7: 3-buffer LDS rotation, ONE barrier per K-step, prefetch depth 2,
//     counted vmcnt(6)/(4) (older loads had 2 full steps of flight), setprio
//     around MFMA cluster. Epoch-safety: STAGE in epoch i targets
//     buf[(i+2)%3] == buf[(i-1)%3], whose readers all finished before BAR_i
//     (ds_reads are lgkm-gated before each wave's MFMAs). SCHEDB after BAR
//     stops the compiler hoisting ds_reads/glds across the barrier.
//     Numerics identical to R6 (fp16 2-product split).
// Buffer plan (no extra allocs):
//   d_ws [64MB]: tgtH (until gemm2) -> attnB | combB (for gemm3)
//   d_out ctx region [64MB]: WH|WL (until gemm1) -> topH|topL (until gemm3)
//   d_out attn region [64MB]: xtH (until gemm2) -> scores/attn

typedef float    floatx4 __attribute__((ext_vector_type(4)));
typedef short    short8  __attribute__((ext_vector_type(8)));
typedef short    short4v __attribute__((ext_vector_type(4)));
typedef _Float16 half8   __attribute__((ext_vector_type(8)));

constexpr int Bb = 16, Cc = 1024, Tt = 1024, Ss = 1024;
#define SCALE_W 0.70710678118654752440f

__device__ __forceinline__ floatx4 mfma16(short8 a, short8 b, floatx4 c) {
  return __builtin_amdgcn_mfma_f32_16x16x32_f16(
      __builtin_bit_cast(half8, a), __builtin_bit_cast(half8, b), c, 0, 0, 0);
}
__device__ __forceinline__ unsigned short f2fh(float f) {  // RNE
  return __builtin_bit_cast(unsigned short, (_Float16)f);
}
__device__ __forceinline__ float fh2f(unsigned short h) {
  return (float)__builtin_bit_cast(_Float16, h);
}
#define GLDS16(g, l)                                        \
  __builtin_amdgcn_global_load_lds(                         \
      (const __attribute__((address_space(1))) void*)(g),   \
      (__attribute__((address_space(3))) void*)(l), 16, 0, 0)
#define WAIT_VM6 asm volatile("s_waitcnt vmcnt(6)" ::: "memory")
#define WAIT_VM4 asm volatile("s_waitcnt vmcnt(4)" ::: "memory")
#define WAIT_VM0 asm volatile("s_waitcnt vmcnt(0)" ::: "memory")
#define BAR __builtin_amdgcn_s_barrier()
#define SCHEDB __builtin_amdgcn_sched_barrier(0)
#define PRIO1 __builtin_amdgcn_s_setprio(1)
#define PRIO0 __builtin_amdgcn_s_setprio(0)

// ---------------------------------------------------------------------------
// Elementwise fp32 -> hi/lo fp16 planes (for W).
// ---------------------------------------------------------------------------
__global__ __launch_bounds__(256) void split_kernel(
    const float* __restrict__ in, unsigned short* __restrict__ outH,
    unsigned short* __restrict__ outL) {
  size_t i4 = (size_t)blockIdx.x * 256 + threadIdx.x;
  float4 v = ((const float4*)in)[i4];
  float f[4] = {v.x, v.y, v.z, v.w};
  short4v h, lo;
#pragma unroll
  for (int q = 0; q < 4; ++q) {
    unsigned short hh = f2fh(f[q]);
    h[q] = (short)hh;
    lo[q] = (short)f2fh(f[q] - fh2f(hh));
  }
  *(short4v*)(outH + i4 * 4) = h;
  *(short4v*)(outL + i4 * 4) = lo;
}

// ---------------------------------------------------------------------------
// Elementwise fp32 -> fp16 (for comb).
// ---------------------------------------------------------------------------
__global__ __launch_bounds__(256) void cvt_kernel(
    const float* __restrict__ in, unsigned short* __restrict__ out) {
  size_t i4 = (size_t)blockIdx.x * 256 + threadIdx.x;
  float4 v = ((const float4*)in)[i4];
  short4v h;
  h[0] = (short)f2fh(v.x);
  h[1] = (short)f2fh(v.y);
  h[2] = (short)f2fh(v.z);
  h[3] = (short)f2fh(v.w);
  *(short4v*)(out + i4 * 4) = h;
}

// ---------------------------------------------------------------------------
// Transpose + hi/lo split: in[b][i][j] fp32 -> outH/outL[b][j][i] fp16.
// ---------------------------------------------------------------------------
__global__ __launch_bounds__(256) void transpose_split_kernel(
    const float* __restrict__ in, unsigned short* __restrict__ outH,
    unsigned short* __restrict__ outL) {
  __shared__ float tile[64][65];
  const int b = blockIdx.z;
  const int i0 = blockIdx.y * 64;
  const int j0 = blockIdx.x * 64;
  const int tid = threadIdx.x;
  const float* pin = in + ((size_t)b * 1024 + i0) * 1024 + j0;
#pragma unroll
  for (int it = 0; it < 4; ++it) {
    int e = tid + it * 256;
    int r = e >> 4, ch = e & 15;
    float4 v = *(const float4*)(pin + (size_t)r * 1024 + ch * 4);
    tile[r][ch * 4 + 0] = v.x;
    tile[r][ch * 4 + 1] = v.y;
    tile[r][ch * 4 + 2] = v.z;
    tile[r][ch * 4 + 3] = v.w;
  }
  __syncthreads();
#pragma unroll
  for (int it = 0; it < 4; ++it) {
    int e = tid + it * 256;
    int r = e >> 4, ch = e & 15;  // r: out row (j), ch: out col chunk (i)
    short4v h, lo;
#pragma unroll
    for (int q = 0; q < 4; ++q) {
      float f = tile[ch * 4 + q][r];
      unsigned short hh = f2fh(f);
      h[q] = (short)hh;
      lo[q] = (short)f2fh(f - fh2f(hh));
    }
    size_t o = ((size_t)b * 1024 + j0 + r) * 1024 + i0 + ch * 4;
    *(short4v*)(outH + o) = h;
    *(short4v*)(outL + o) = lo;
  }
}

// ---------------------------------------------------------------------------
// Transpose hi-only: in[b][i][j] fp32 -> outH[b][j][i] fp16 (for x).
// ---------------------------------------------------------------------------
__global__ __launch_bounds__(256) void transpose_h_kernel(
    const float* __restrict__ in, unsigned short* __restrict__ outH) {
  __shared__ float tile[64][65];
  const int b = blockIdx.z;
  const int i0 = blockIdx.y * 64;
  const int j0 = blockIdx.x * 64;
  const int tid = threadIdx.x;
  const float* pin = in + ((size_t)b * 1024 + i0) * 1024 + j0;
#pragma unroll
  for (int it = 0; it < 4; ++it) {
    int e = tid + it * 256;
    int r = e >> 4, ch = e & 15;
    float4 v = *(const float4*)(pin + (size_t)r * 1024 + ch * 4);
    tile[r][ch * 4 + 0] = v.x;
    tile[r][ch * 4 + 1] = v.y;
    tile[r][ch * 4 + 2] = v.z;
    tile[r][ch * 4 + 3] = v.w;
  }
  __syncthreads();
#pragma unroll
  for (int it = 0; it < 4; ++it) {
    int e = tid + it * 256;
    int r = e >> 4, ch = e & 15;
    short4v h;
#pragma unroll
    for (int q = 0; q < 4; ++q) h[q] = (short)f2fh(tile[ch * 4 + q][r]);
    size_t o = ((size_t)b * 1024 + j0 + r) * 1024 + i0 + ch * 4;
    *(short4v*)(outH + o) = h;
  }
}

// ---------------------------------------------------------------------------
// GEMM1 (2-product): tgt[t][d] = SCALE*(base[d][t]+bias[d]+sum_c W[d][c]x[c][t])
// m=d, n=t, k=c.  A=WH/WL [m][k] fp16 (glds).  B=xtH [n][k] fp16 (glds).
// 3-buffer rotation, 1 barrier/step, depth-2 prefetch, vmcnt(6).
// ---------------------------------------------------------------------------
__global__ __launch_bounds__(256) void gemm1_kernel(
    const unsigned short* __restrict__ WH, const unsigned short* __restrict__ WL,
    const unsigned short* __restrict__ xH, const float* __restrict__ base,
    const float* __restrict__ bias, unsigned short* __restrict__ tgtH) {
  __shared__ alignas(16) short AsH[3][128 * 32], AsL[3][128 * 32];
  __shared__ alignas(16) short Bs[3][128 * 32];
  const int b = blockIdx.z;
  const int m0 = blockIdx.y * 128;  // d
  const int n0 = blockIdx.x * 128;  // t
  const int tid = threadIdx.x;
  const int wid = tid >> 6, l = tid & 63;
  const int wm = (wid >> 1) * 64, wn = (wid & 1) * 64;
  const int quad = l >> 4, l15 = l & 15;
  const int sq8 = (quad ^ ((l15 >> 1) & 3)) * 8;  // swizzled read granule

  floatx4 acc[4][4];
#pragma unroll
  for (int i = 0; i < 4; ++i)
#pragma unroll
    for (int j = 0; j < 4; ++j) acc[i][j] = (floatx4){0.f, 0.f, 0.f, 0.f};

  const size_t aoff = (size_t)m0 * Cc;
  const size_t xoff = ((size_t)b * Tt + n0) * Cc;
  const int rb0 = wid * 32, rb1 = wid * 32 + 16;
  const int lrow = l >> 2;
  const int lcol = (((l & 3) ^ ((lrow >> 1) & 3)) * 8);  // pre-swizzled source

#define STAGE1(kk, bb)                                                          \
  {                                                                             \
    GLDS16(WH + aoff + (size_t)(rb0 + lrow) * Cc + (kk) + lcol, &AsH[bb][rb0 * 32]); \
    GLDS16(WH + aoff + (size_t)(rb1 + lrow) * Cc + (kk) + lcol, &AsH[bb][rb1 * 32]); \
    GLDS16(WL + aoff + (size_t)(rb0 + lrow) * Cc + (kk) + lcol, &AsL[bb][rb0 * 32]); \
    GLDS16(WL + aoff + (size_t)(rb1 + lrow) * Cc + (kk) + lcol, &AsL[bb][rb1 * 32]); \
    GLDS16(xH + xoff + (size_t)(rb0 + lrow) * Cc + (kk) + lcol, &Bs[bb][rb0 * 32]); \
    GLDS16(xH + xoff + (size_t)(rb1 + lrow) * Cc + (kk) + lcol, &Bs[bb][rb1 * 32]); \
  }

  STAGE1(0, 0);
  STAGE1(32, 1);
  int cur = 0;
  constexpr int NS = Cc / 32;  // 32 steps
  for (int i = 0; i < NS; ++i) {
    if (i + 1 < NS) {
      WAIT_VM6;  // buf[cur] loads (issued 2 steps ago) done; newer stay in flight
    } else {
      WAIT_VM0;
    }
    BAR;     // all waves' buf[cur] portions complete
    SCHEDB;  // no ds_read/glds hoisted above the barrier
    short8 aH[4], aL[4], bf[4];
#pragma unroll
    for (int ii = 0; ii < 4; ++ii) {
      aH[ii] = *(const short8*)&AsH[cur][(wm + ii * 16 + l15) * 32 + sq8];
      aL[ii] = *(const short8*)&AsL[cur][(wm + ii * 16 + l15) * 32 + sq8];
      bf[ii] = *(const short8*)&Bs[cur][(wn + ii * 16 + l15) * 32 + sq8];
    }
    if (i + 2 < NS) {
      int b2 = cur + 2;
      if (b2 >= 3) b2 -= 3;
      STAGE1(32 * (i + 2), b2);  // targets buf computed in epoch i-1: safe
    }
    PRIO1;
#pragma unroll
    for (int ii = 0; ii < 4; ++ii)
#pragma unroll
      for (int jj = 0; jj < 4; ++jj) {
        acc[ii][jj] = mfma16(aH[ii], bf[jj], acc[ii][jj]);
        acc[ii][jj] = mfma16(aL[ii], bf[jj], acc[ii][jj]);
      }
    PRIO0;
    cur = (cur + 1 == 3) ? 0 : cur + 1;
  }
#undef STAGE1
  // Epilogue: + bias + base, scale, store hi plane [t][c]
#pragma unroll
  for (int i = 0; i < 4; ++i) {
    int dbase = m0 + wm + i * 16 + quad * 4;
    float4 bv = *(const float4*)(bias + dbase);
    float bvv[4] = {bv.x, bv.y, bv.z, bv.w};
#pragma unroll
    for (int j = 0; j < 4; ++j) {
      int t = n0 + wn + j * 16 + l15;
      short4v h;
#pragma unroll
      for (int r = 0; r < 4; ++r) {
        float v = (acc[i][j][r] + bvv[r] +
                   base[((size_t)b * Cc + dbase + r) * Tt + t]) * SCALE_W;
        h[r] = (short)f2fh(v);
      }
      size_t o = ((size_t)b * Tt + t) * Cc + dbase;
      *(short4v*)(tgtH + o) = h;
    }
  }
}

// ---------------------------------------------------------------------------
// GEMM2 (2-product): scores[t][s] = sum_c tgt[t][c] top_t[s][c]
// m=t, n=s, k=c.  A=tgtH; B=topH/topL.  Same 3-buffer/1-barrier schedule.
// ---------------------------------------------------------------------------
__global__ __launch_bounds__(256) void gemm2_kernel(
    const unsigned short* __restrict__ tgtH,
    const unsigned short* __restrict__ topH, const unsigned short* __restrict__ topL,
    float* __restrict__ scores) {
  __shared__ alignas(16) short As[3][128 * 32];
  __shared__ alignas(16) short BsH[3][128 * 32], BsL[3][128 * 32];
  const int b = blockIdx.z;
  const int t0 = blockIdx.y * 128;  // m
  const int s0 = blockIdx.x * 128;  // n
  const int tid = threadIdx.x;
  const int wid = tid >> 6, l = tid & 63;
  const int wm = (wid >> 1) * 64, wn = (wid & 1) * 64;
  const int quad = l >> 4, l15 = l & 15;
  const int sq8 = (quad ^ ((l15 >> 1) & 3)) * 8;

  floatx4 acc[4][4];
#pragma unroll
  for (int i = 0; i < 4; ++i)
#pragma unroll
    for (int j = 0; j < 4; ++j) acc[i][j] = (floatx4){0.f, 0.f, 0.f, 0.f};

  const size_t aoff = ((size_t)b * Tt + t0) * Cc;
  const size_t boff = ((size_t)b * Ss + s0) * Cc;
  const int rb0 = wid * 32, rb1 = wid * 32 + 16;
  const int lrow = l >> 2;
  const int lcol = (((l & 3) ^ ((lrow >> 1) & 3)) * 8);

#define STAGE2(kk, bb)                                                          \
  {                                                                             \
    GLDS16(tgtH + aoff + (size_t)(rb0 + lrow) * Cc + (kk) + lcol, &As[bb][rb0 * 32]); \
    GLDS16(tgtH + aoff + (size_t)(rb1 + lrow) * Cc + (kk) + lcol, &As[bb][rb1 * 32]); \
    GLDS16(topH + boff + (size_t)(rb0 + lrow) * Cc + (kk) + lcol, &BsH[bb][rb0 * 32]); \
    GLDS16(topH + boff + (size_t)(rb1 + lrow) * Cc + (kk) + lcol, &BsH[bb][rb1 * 32]); \
    GLDS16(topL + boff + (size_t)(rb0 + lrow) * Cc + (kk) + lcol, &BsL[bb][rb0 * 32]); \
    GLDS16(topL + boff + (size_t)(rb1 + lrow) * Cc + (kk) + lcol, &BsL[bb][rb1 * 32]); \
  }

  STAGE2(0, 0);
  STAGE2(32, 1);
  int cur = 0;
  constexpr int NS = Cc / 32;
  for (int i = 0; i < NS; ++i) {
    if (i + 1 < NS) {
      WAIT_VM6;
    } else {
      WAIT_VM0;
    }
    BAR;
    SCHEDB;
    short8 af[4], bH[4], bL[4];
#pragma unroll
    for (int ii = 0; ii < 4; ++ii) {
      af[ii] = *(const short8*)&As[cur][(wm + ii * 16 + l15) * 32 + sq8];
      bH[ii] = *(const short8*)&BsH[cur][(wn + ii * 16 + l15) * 32 + sq8];
      bL[ii] = *(const short8*)&BsL[cur][(wn + ii * 16 + l15) * 32 + sq8];
    }
    if (i + 2 < NS) {
      int b2 = cur + 2;
      if (b2 >= 3) b2 -= 3;
      STAGE2(32 * (i + 2), b2);
    }
    PRIO1;
#pragma unroll
    for (int ii = 0; ii < 4; ++ii)
#pragma unroll
      for (int jj = 0; jj < 4; ++jj) {
        acc[ii][jj] = mfma16(af[ii], bH[jj], acc[ii][jj]);
        acc[ii][jj] = mfma16(af[ii], bL[jj], acc[ii][jj]);
      }
    PRIO0;
    cur = (cur + 1 == 3) ? 0 : cur + 1;
  }
#undef STAGE2
#pragma unroll
  for (int i = 0; i < 4; ++i)
#pragma unroll
    for (int j = 0; j < 4; ++j) {
      int s_ = s0 + wn + j * 16 + l15;
#pragma unroll
      for (int r = 0; r < 4; ++r) {
        int t_ = t0 + wm + i * 16 + quad * 4 + r;
        scores[((size_t)b * Tt + t_) * Ss + s_] = acc[i][j][r];
      }
    }
}

// ---------------------------------------------------------------------------
// Softmax over S=1024, one block per row, in place (fp32) + fp16 copy out.
// ---------------------------------------------------------------------------
__global__ __launch_bounds__(256) void softmax_kernel(
    float* __restrict__ attn, unsigned short* __restrict__ attnB) {
  __shared__ float red[8];
  float* p = attn + (size_t)blockIdx.x * Ss;
  const int tid = threadIdx.x;
  float4 v = *(float4*)(p + tid * 4);
  float m = fmaxf(fmaxf(v.x, v.y), fmaxf(v.z, v.w));
#pragma unroll
  for (int off = 1; off < 64; off <<= 1) m = fmaxf(m, __shfl_xor(m, off));
  const int wave = tid >> 6, lane = tid & 63;
  if (lane == 0) red[wave] = m;
  __syncthreads();
  m = fmaxf(fmaxf(red[0], red[1]), fmaxf(red[2], red[3]));
  v.x = __expf(v.x - m);
  v.y = __expf(v.y - m);
  v.z = __expf(v.z - m);
  v.w = __expf(v.w - m);
  float s = v.x + v.y + v.z + v.w;
#pragma unroll
  for (int off = 1; off < 64; off <<= 1) s += __shfl_xor(s, off);
  if (lane == 0) red[4 + wave] = s;
  __syncthreads();
  s = red[4] + red[5] + red[6] + red[7];
  float inv = 1.0f / s;
  v.x *= inv;
  v.y *= inv;
  v.z *= inv;
  v.w *= inv;
  *(float4*)(p + tid * 4) = v;
  short4v h;
  h[0] = (short)f2fh(v.x);
  h[1] = (short)f2fh(v.y);
  h[2] = (short)f2fh(v.z);
  h[3] = (short)f2fh(v.w);
  *(short4v*)(attnB + (size_t)blockIdx.x * Ss + tid * 4) = h;
}

// ---------------------------------------------------------------------------
// GEMM3 (plain fp16): ctx[c][t] = sum_s comb[c][s] attn[t][s]
// m=c, n=t, k=s.  3-buffer/1-barrier schedule, vmcnt(4).
// ---------------------------------------------------------------------------
__global__ __launch_bounds__(256) void gemm3_kernel(
    const unsigned short* __restrict__ combB,
    const unsigned short* __restrict__ attnB, float* __restrict__ ctx) {
  __shared__ alignas(16) short As[3][128 * 32], Bs[3][128 * 32];
  const int b = blockIdx.z;
  const int m0 = blockIdx.y * 128;  // c
  const int n0 = blockIdx.x * 128;  // t
  const int tid = threadIdx.x;
  const int wid = tid >> 6, l = tid & 63;
  const int wm = (wid >> 1) * 64, wn = (wid & 1) * 64;
  const int quad = l >> 4, l15 = l & 15;
  const int sq8 = (quad ^ ((l15 >> 1) & 3)) * 8;

  floatx4 acc[4][4];
#pragma unroll
  for (int i = 0; i < 4; ++i)
#pragma unroll
    for (int j = 0; j < 4; ++j) acc[i][j] = (floatx4){0.f, 0.f, 0.f, 0.f};

  const size_t aoff = ((size_t)b * Cc + m0) * Ss;
  const size_t boff = ((size_t)b * Tt + n0) * Ss;
  const int rb0 = wid * 32, rb1 = wid * 32 + 16;
  const int lrow = l >> 2;
  const int lcol = (((l & 3) ^ ((lrow >> 1) & 3)) * 8);

#define STAGE3(kk, bb)                                                          \
  {                                                                             \
    GLDS16(combB + aoff + (size_t)(rb0 + lrow) * Ss + (kk) + lcol, &As[bb][rb0 * 32]); \
    GLDS16(combB + aoff + (size_t)(rb1 + lrow) * Ss + (kk) + lcol, &As[bb][rb1 * 32]); \
    GLDS16(attnB + boff + (size_t)(rb0 + lrow) * Ss + (kk) + lcol, &Bs[bb][rb0 * 32]); \
    GLDS16(attnB + boff + (size_t)(rb1 + lrow) * Ss + (kk) + lcol, &Bs[bb][rb1 * 32]); \
  }

  STAGE3(0, 0);
  STAGE3(32, 1);
  int cur = 0;
  constexpr int NS = Ss / 32;
  for (int i = 0; i < NS; ++i) {
    if (i + 1 < NS) {
      WAIT_VM4;
    } else {
      WAIT_VM0;
    }
    BAR;
    SCHEDB;
    short8 af[4], bf[4];
#pragma unroll
    for (int ii = 0; ii < 4; ++ii) {
      af[ii] = *(const short8*)&As[cur][(wm + ii * 16 + l15) * 32 + sq8];
      bf[ii] = *(const short8*)&Bs[cur][(wn + ii * 16 + l15) * 32 + sq8];
    }
    if (i + 2 < NS) {
      int b2 = cur + 2;
      if (b2 >= 3) b2 -= 3;
      STAGE3(32 * (i + 2), b2);
    }
    PRIO1;
#pragma unroll
    for (int ii = 0; ii < 4; ++ii)
#pragma unroll
      for (int jj = 0; jj < 4; ++jj) acc[ii][jj] = mfma16(af[ii], bf[jj], acc[ii][jj]);
    PRIO0;
    cur = (cur + 1 == 3) ? 0 : cur + 1;
  }
#undef STAGE3
#pragma unroll
  for (int i = 0; i < 4; ++i)
#pragma unroll
    for (int j = 0; j < 4; ++j) {
      int t_ = n0 + wn + j * 16 + l15;
#pragma unroll
      for (int r = 0; r < 4; ++r) {
        int c_ = m0 + wm + i * 16 + quad * 4 + r;
        ctx[((size_t)b * Cc + c_) * Tt + t_] = acc[i][j][r];
      }
    }
}

extern "C" void kernel_launch(void* const* d_in, const int* in_sizes, int n_in,
                              void* d_out, int out_size, void* d_ws,
                              size_t ws_size, hipStream_t stream) {
  const float* base = (const float*)d_in[0];  // [B,C,T]
  const float* x = (const float*)d_in[1];     // [B,C,T]
  const float* top = (const float*)d_in[2];   // [B,C,S]
  const float* comb = (const float*)d_in[3];  // [B,C,S]
  const float* W = (const float*)d_in[4];     // [C,C]
  const float* bias = (const float*)d_in[5];  // [C]

  const size_t NE = (size_t)Bb * 1024 * 1024;  // 16M elements per plane
  float* ctx_out = (float*)d_out;              // [B,C,T]
  float* attn = (float*)d_out + NE;            // [B,T,S]
  // temp planes in dead regions:
  unsigned short* WH = (unsigned short*)d_out;  // ctx region, until gemm1 done
  unsigned short* WL = WH + (size_t)Cc * Cc;
  unsigned short* topH = (unsigned short*)d_out;  // ctx region, until gemm3
  unsigned short* topL = topH + NE;
  unsigned short* xtH = (unsigned short*)attn;  // attn region, until gemm2
  unsigned short* tgtH = (unsigned short*)d_ws;  // ws, until gemm2 done
  unsigned short* attnB = (unsigned short*)d_ws;  // ws reuse after gemm2
  unsigned short* combB = attnB + NE;

  dim3 blk(256);
  // 1. W -> WH/WL (ctx region; consumed by gemm1 before top transpose)
  split_kernel<<<dim3((Cc * Cc) / 1024), blk, 0, stream>>>(W, WH, WL);
  // 2. x -> xtH (attn region)
  transpose_h_kernel<<<dim3(16, 16, Bb), blk, 0, stream>>>(x, xtH);
  // 3. gemm1 -> tgtH (ws)
  gemm1_kernel<<<dim3(Tt / 128, Cc / 128, Bb), blk, 0, stream>>>(
      WH, WL, xtH, base, bias, tgtH);
  // 4. top -> top planes (ctx region; overwrites WH/WL, now dead)
  transpose_split_kernel<<<dim3(16, 16, Bb), blk, 0, stream>>>(top, topH, topL);
  // 5. gemm2 -> scores (attn region; overwrites xtH, now dead)
  gemm2_kernel<<<dim3(Ss / 128, Tt / 128, Bb), blk, 0, stream>>>(
      tgtH, topH, topL, attn);
  // 6. softmax in place + fp16 copy into ws (tgtH now dead)
  softmax_kernel<<<dim3(Bb * Tt), blk, 0, stream>>>(attn, attnB);
  // 7. comb -> fp16 (ws second half)
  cvt_kernel<<<dim3(NE / 1024), blk, 0, stream>>>(comb, combB);
  // 8. gemm3 -> ctx (overwrites top planes, now dead)
  gemm3_kernel<<<dim3(Tt / 128, Cc / 128, Bb), blk, 0, stream>>>(
      combB, attnB, ctx_out);
}